// Round 5
// baseline (742.836 us; speedup 1.0000x reference)
//
#include <hip/hip_runtime.h>

#define P_    4
#define K_    2048
#define D_    128
#define B_    16
#define HW_   784
#define N_    (B_ * HW_)          // 12544
#define C_    512

#define OUT0_SZ   (B_ * C_ * HW_) // 6422528
#define QLOSS_OFF OUT0_SZ
#define OUT2_OFF  (OUT0_SZ + 1)

typedef short  short8 __attribute__((ext_vector_type(8)));
typedef float  f32x4  __attribute__((ext_vector_type(4)));

__device__ __forceinline__ short f2bf(float x) {
    union { float f; unsigned u; } a; a.f = x;
    unsigned r = a.u + 0x7FFF + ((a.u >> 16) & 1);   // RNE
    return (short)(r >> 16);
}

// ---------------- prep: codebook -> bf16 + squared norms ----------------
__global__ __launch_bounds__(256) void vq_prep(const float* __restrict__ cb,
                                               short* __restrict__ cbb,
                                               float* __restrict__ cnorm) {
    int wave = threadIdx.x >> 6;
    int lane = threadIdx.x & 63;
    int row  = blockIdx.x * 4 + wave;            // 0 .. P_*K_-1
    const float* src = cb + (size_t)row * D_;
    float2 v = *(const float2*)(src + lane * 2);
    cbb[(size_t)row * D_ + lane * 2 + 0] = f2bf(v.x);
    cbb[(size_t)row * D_ + lane * 2 + 1] = f2bf(v.y);
    float s = v.x * v.x + v.y * v.y;
    #pragma unroll
    for (int m = 1; m < 64; m <<= 1) s += __shfl_xor(s, m, 64);
    if (lane == 0) cnorm[row] = s;
}

// ---------------- main: GEMM + softmax/argmax + zq gather + loss ----------------
// block = 512 thr (8 waves), one p, 16 n-rows, full K=2048 cols.
// SWAPPED MFMA operands: A = codebook frag, B = z frag -> C col (lane&15) is
// the n-row, so each lane holds 64 logits of ONE row. Softmax is in-lane +
// 2 shfl_xor; out2 stores are direct per-lane dwordx4 at kernel end (no LDS
// transpose, no barriers, no store drain). 4 barriers total per block.
__global__ __launch_bounds__(512, 4) void vq_main(const float* __restrict__ z,
                                                  const short* __restrict__ cbb,
                                                  const float* __restrict__ cnorm,
                                                  const float* __restrict__ cb,
                                                  float* __restrict__ out0,
                                                  float* __restrict__ qloss,
                                                  float* __restrict__ out2) {
    __shared__ short As[16][136];        // [n-row][k], +8 pad
    __shared__ float wsum[8][16];
    __shared__ float wmax[8][16];
    __shared__ int   wmidx[8][16];
    __shared__ int   ridx[16];           // winning codebook index per row
    __shared__ float lsum[8];

    const int bx  = blockIdx.x;
    const int p   = bx / (N_ / 16);      // 784 tiles per p (same-p blocks adjacent -> L2 reuse)
    const int nt  = bx % (N_ / 16);
    const int b   = nt / 49;             // HW_=784 = 49*16, tiles never cross b
    const int hw0 = (nt % 49) * 16;
    const int n0  = nt * 16;

    // --- stage A tile (16 rows x 128 k) as bf16, transposed, in LDS ---
    // keep the fp32 z values in registers for the loss/zq step
    const int kz  = threadIdx.x >> 2;    // 0..127
    const int q4  = threadIdx.x & 3;     // 0..3 (rows q4*4 .. q4*4+3)
    float4 zv;
    {
        const float* src = z + ((size_t)b * C_ + p * D_ + kz) * HW_ + hw0 + q4 * 4;
        zv = *(const float4*)src;
        int r0 = q4 * 4;
        As[r0 + 0][kz] = f2bf(zv.x);  As[r0 + 1][kz] = f2bf(zv.y);
        As[r0 + 2][kz] = f2bf(zv.z);  As[r0 + 3][kz] = f2bf(zv.w);
    }
    __syncthreads();                     // B1

    const int wave = threadIdx.x >> 6;
    const int lane = threadIdx.x & 63;
    const int llo  = lane & 15;          // n-row owned by this lane
    const int lhi  = lane >> 4;          // k-quad / col-quad

    // z fragments (MFMA B operand): lane holds z[row=llo][k = s*32 + lhi*8 ..+8]
    short8 zf[4];
    #pragma unroll
    for (int s = 0; s < 4; s++)
        zf[s] = *(const short8*)&As[llo][s * 32 + lhi * 8];

    // codebook fragments (MFMA A operand): row = wave*256 + ct*16 + llo
    const short* bptr = cbb + ((size_t)(p * K_ + wave * 256 + llo) * D_ + lhi * 8);

    f32x4 acc[16];
    #pragma unroll
    for (int ct = 0; ct < 16; ct++) {
        const short* bp = bptr + (size_t)ct * 16 * D_;
        short8 b0 = *(const short8*)(bp +  0);
        short8 b1 = *(const short8*)(bp + 32);
        short8 b2 = *(const short8*)(bp + 64);
        short8 b3 = *(const short8*)(bp + 96);
        f32x4 a = {0.f, 0.f, 0.f, 0.f};
        a = __builtin_amdgcn_mfma_f32_16x16x32_bf16(b0, zf[0], a, 0, 0, 0);
        a = __builtin_amdgcn_mfma_f32_16x16x32_bf16(b1, zf[1], a, 0, 0, 0);
        a = __builtin_amdgcn_mfma_f32_16x16x32_bf16(b2, zf[2], a, 0, 0, 0);
        a = __builtin_amdgcn_mfma_f32_16x16x32_bf16(b3, zf[3], a, 0, 0, 0);
        acc[ct] = a;
    }

    // --- epilogue: exp (logits tiny: no max-sub), lane-local sum/argmax ---
    // C layout: col(lane&15) = n-row llo; row(lhi*4 + r) = cb col within tile
    float rs = 0.f;
    float mx = -1e30f;
    int   mi = 0;
    const float* cnp = cnorm + p * K_ + wave * 256 + lhi * 4;
    #pragma unroll
    for (int ct = 0; ct < 16; ct++) {
        f32x4 c4 = *(const f32x4*)(cnp + ct * 16);
        #pragma unroll
        for (int r = 0; r < 4; r++) {
            float s = 4.0f * acc[ct][r] - 2.0f * c4[r];
            float e = __expf(s);
            acc[ct][r] = e;
            rs += e;
            if (e > mx) { mx = e; mi = wave * 256 + ct * 16 + lhi * 4 + r; }
        }
    }
    // combine the 4 lanes (lhi groups) holding the same row llo
    #pragma unroll
    for (int m = 16; m < 64; m <<= 1) {
        rs += __shfl_xor(rs, m, 64);
        float om = __shfl_xor(mx, m, 64);
        int   oi = __shfl_xor(mi, m, 64);
        if (om > mx || (om == mx && oi < mi)) { mx = om; mi = oi; }
    }
    if (lhi == 0) {
        wsum[wave][llo]  = rs;
        wmax[wave][llo]  = mx;
        wmidx[wave][llo] = mi;
    }
    __syncthreads();                     // B2

    float ssum = 0.f;
    #pragma unroll
    for (int w2 = 0; w2 < 8; w2++) ssum += wsum[w2][llo];
    const float inv = 1.0f / ssum;

    if (threadIdx.x < 16) {
        int row = threadIdx.x;
        float m0 = wmax[0][row]; int i0 = wmidx[0][row];
        #pragma unroll
        for (int w2 = 1; w2 < 8; w2++) {
            float mm = wmax[w2][row]; int ii = wmidx[w2][row];
            if (mm > m0 || (mm == m0 && ii < i0)) { m0 = mm; i0 = ii; }
        }
        ridx[row] = i0;
    }
    __syncthreads();                     // B3

    // --- fused zq gather + out0 store + q_loss (fp32, from registers) ---
    {
        const float* cbp = cb + ((size_t)p * K_) * D_ + kz;
        float4 q;
        q.x = cbp[(size_t)ridx[q4 * 4 + 0] * D_];
        q.y = cbp[(size_t)ridx[q4 * 4 + 1] * D_];
        q.z = cbp[(size_t)ridx[q4 * 4 + 2] * D_];
        q.w = cbp[(size_t)ridx[q4 * 4 + 3] * D_];
        float* dst = out0 + ((size_t)b * C_ + p * D_ + kz) * HW_ + hw0 + q4 * 4;
        *(float4*)dst = q;
        float dx = q.x - zv.x, dy = q.y - zv.y;
        float dz = q.z - zv.z, dw = q.w - zv.w;
        float loss = dx * dx + dy * dy + dz * dz + dw * dw;
        #pragma unroll
        for (int m = 1; m < 64; m <<= 1) loss += __shfl_xor(loss, m, 64);
        if (lane == 0) lsum[wave] = loss;
    }
    __syncthreads();                     // B4
    if (threadIdx.x == 0) {
        float tot = 0.f;
        #pragma unroll
        for (int w2 = 0; w2 < 8; w2++) tot += lsum[w2];
        // q_loss = (1 + BETA) * mean((zq - zf)^2), BETA = 0.25
        atomicAdd(qloss, tot * (1.25f / (float)(P_ * (size_t)N_ * D_)));
    }

    // --- normalize + store probs: direct per-lane dwordx4, fire-and-forget ---
    // lanes sharing llo (4 lhi values) form 64 B contiguous segments.
    float* obase = out2 + (size_t)(n0 + llo) * (P_ * K_) + p * K_ + wave * 256 + lhi * 4;
    #pragma unroll
    for (int ct = 0; ct < 16; ct++) {
        f32x4 v = acc[ct] * inv;
        *(f32x4*)(obase + ct * 16) = v;
    }
}

extern "C" void kernel_launch(void* const* d_in, const int* in_sizes, int n_in,
                              void* d_out, int out_size, void* d_ws, size_t ws_size,
                              hipStream_t stream) {
    const float* z  = (const float*)d_in[0];
    const float* cb = (const float*)d_in[1];
    float* out = (float*)d_out;

    float* ws_cnorm = (float*)((char*)d_ws + (256 << 10));     //  32 KB
    short* ws_cbb   = (short*)((char*)d_ws + (512 << 10));     //   2 MB

    hipMemsetAsync(out + QLOSS_OFF, 0, sizeof(float), stream);
    vq_prep<<<(P_ * K_) / 4, 256, 0, stream>>>(cb, ws_cbb, ws_cnorm);
    vq_main<<<P_ * (N_ / 16), 512, 0, stream>>>(z, ws_cbb, ws_cnorm, cb,
                                                out, out + QLOSS_OFF,
                                                out + OUT2_OFF);
}